// Round 12
// baseline (158.785 us; speedup 1.0000x reference)
//
#include <hip/hip_runtime.h>
#include <math.h>

#define H2 256
#define MAXDEG 128
#define APAD 520   // sA row stride (halves): 1040B rows -> 2-way banks (free)
#define HPAD 264   // hbuf row stride (halves): 528B rows -> 2-way banks (free)

typedef _Float16 f16x8 __attribute__((ext_vector_type(8)));
typedef _Float16 f16x4 __attribute__((ext_vector_type(4)));
typedef float f32x4 __attribute__((ext_vector_type(4)));

// ---------------------------------------------------------------------------
// K1: prep + scatter (cursor pre-zeroed by hipMemsetAsync).
//  - blocks 0..47: one 64x64 W-transpose tile each via LDS (both sides
//    coalesced; LDS stride 66 halves -> conflict-free transpose read)
//  - all blocks: 8 cat rows (fp32 -> fp16, coalesced)
//  - all blocks: 256 edges scatter (1 int atomic each)
__global__ __launch_bounds__(256) void prep_scatter(
        const float* __restrict__ nf, const float* __restrict__ W1,
        const float* __restrict__ W2, const int* __restrict__ esrc,
        const int* __restrict__ edst, int* __restrict__ cursor,
        int* __restrict__ bucket, _Float16* __restrict__ cat,
        _Float16* __restrict__ W1t, _Float16* __restrict__ W2t,
        int n, int E) {
    __shared__ _Float16 tile[64 * 66];
    int tid = threadIdx.x;
    int blk = blockIdx.x;

    // --- W transpose tiles (blocks 0..47) ---
    if (blk < 48) {
        const float* Wsrc;
        _Float16* Wdst;
        int k0, n0, ldK;
        if (blk < 32) {            // W1 512(k) x 256(n) -> W1t [256][512]
            int kt = blk >> 2, nt = blk & 3;
            k0 = kt * 64; n0 = nt * 64; ldK = 512;
            Wsrc = W1; Wdst = W1t;
        } else {                   // W2 256 x 256 -> W2t [256][256]
            int t2 = blk - 32;
            int kt = t2 >> 2, nt = t2 & 3;
            k0 = kt * 64; n0 = nt * 64; ldK = 256;
            Wsrc = W2; Wdst = W2t;
        }
        for (int idx = tid; idx < 64 * 64; idx += 256) {
            int r = idx >> 6, c = idx & 63;   // r: k-offset, c: n-offset
            tile[r * 66 + c] = (_Float16)Wsrc[(size_t)(k0 + r) * 256 + n0 + c];
        }
        __syncthreads();
        for (int idx = tid; idx < 64 * 64; idx += 256) {
            int cc = idx >> 6, rr = idx & 63; // out: n = n0+cc, k = k0+rr
            Wdst[(size_t)(n0 + cc) * ldK + k0 + rr] = tile[rr * 66 + cc];
        }
    }

    // --- cat convert: 8 rows per block, 2 per wave ---
    int wid  = tid >> 6;
    int lane = tid & 63;
#pragma unroll
    for (int t = 0; t < 2; ++t) {
        int row = blk * 8 + wid * 2 + t;
        if (row < n) {
            float4 v = ((const float4*)nf)[(size_t)row * 64 + lane];
            f16x4 h;
            h.x = (_Float16)v.x; h.y = (_Float16)v.y;
            h.z = (_Float16)v.z; h.w = (_Float16)v.w;
            *(f16x4*)&cat[(size_t)row * 256 + lane * 4] = h;
        }
    }

    // --- edge scatter ---
    int flat = blk * 256 + tid;
    if (flat < E) {
        int d = edst[flat];
        int s = esrc[flat];
        int r = atomicAdd(&cursor[d], 1);
        if (r < MAXDEG) bucket[d * MAXDEG + r] = s;
    }
}

// ---------------------------------------------------------------------------
// K2: fully fused. Phase 0a: stage cat rows -> sA cols [0,256).
// Phase 0b: wave w gathers pooled for rows 4w..4w+3 (paired-row b128: lanes
// 0-31 row e, lanes 32-63 row e+1; halves merged via shfl_down 32), writes
// fp16 into sA cols [256,512). Then out = tanh((sA@W1t+b1)@W2t+b2).
// 256 thr / 4 waves; M-tile 16 (grid 625); wave n-tile 64 (j=4).
// W fragments via depth-4 register pipeline; A via LDS; h via LDS.
__global__ __launch_bounds__(256, 2) void gemm12agg(
        const float* __restrict__ nf, const _Float16* __restrict__ cat,
        const int* __restrict__ cursor, const int* __restrict__ bucket,
        const _Float16* __restrict__ W1t, const _Float16* __restrict__ W2t,
        const float* __restrict__ b1, const float* __restrict__ b2,
        float* __restrict__ out, int M) {
    __shared__ _Float16 sA[16 * APAD];     // 16.3 KB
    __shared__ _Float16 hbuf[16 * HPAD];   //  8.3 KB

    int tid = threadIdx.x, lane = tid & 63, wid = tid >> 6;   // wid 0..3
    int m0 = blockIdx.x * 16;
    int wn = wid * 64;
    int fm = lane & 15;
    int q  = lane >> 4;
    int fk = q * 8;

    // ---- phase 0a: stage cat -> sA cols [0,256): 16 rows x 32 b128 groups
    for (int idx = tid; idx < 16 * 32; idx += 256) {
        int row = idx >> 5, g = (idx & 31) * 8;
        int r = m0 + row; if (r >= M) r = M - 1;
        *(uint4*)&sA[row * APAD + g] = *(const uint4*)&cat[(size_t)r * 256 + g];
    }

    // ---- phase 0b: gather pooled for rows 4*wid .. 4*wid+3
    int half = lane >> 5;          // 0: even edge of pair, 1: odd edge
    int c8   = (lane & 31) * 8;    // col base (halves), 16B/lane
#pragma unroll
    for (int t = 0; t < 4; ++t) {
        int rw = wid * 4 + t;
        int node = m0 + rw; if (node >= M) node = M - 1;
        int deg  = cursor[node];
        int degc = deg < MAXDEG ? deg : MAXDEG;
        const int* bk = bucket + (size_t)node * MAXDEG;
        float acc[8] = {0.f, 0.f, 0.f, 0.f, 0.f, 0.f, 0.f, 0.f};
        int e = 0;
#pragma unroll 8
        for (; e + 2 <= degc; e += 2) {
            int s = bk[e + half];
            f16x8 v = *(const f16x8*)&cat[(size_t)s * 256 + c8];
#pragma unroll
            for (int k = 0; k < 8; ++k) acc[k] += (float)v[k];
        }
        if (e < degc && half == 0) {   // odd tail edge: lower half only
            int s = bk[e];
            f16x8 v = *(const f16x8*)&cat[(size_t)s * 256 + c8];
#pragma unroll
            for (int k = 0; k < 8; ++k) acc[k] += (float)v[k];
        }
        float tot[8];
#pragma unroll
        for (int k = 0; k < 8; ++k) tot[k] = acc[k] + __shfl_down(acc[k], 32);
        if (lane < 32) {
            float4 s0 = ((const float4*)nf)[(size_t)node * 64 + lane * 2];
            float4 s1 = ((const float4*)nf)[(size_t)node * 64 + lane * 2 + 1];
            float fd = (float)deg;
            f16x8 o;
            o[0] = (_Float16)(fd * s0.x - tot[0]);
            o[1] = (_Float16)(fd * s0.y - tot[1]);
            o[2] = (_Float16)(fd * s0.z - tot[2]);
            o[3] = (_Float16)(fd * s0.w - tot[3]);
            o[4] = (_Float16)(fd * s1.x - tot[4]);
            o[5] = (_Float16)(fd * s1.y - tot[5]);
            o[6] = (_Float16)(fd * s1.z - tot[6]);
            o[7] = (_Float16)(fd * s1.w - tot[7]);
            *(f16x8*)&sA[rw * APAD + 256 + lane * 8] = o;
        }
    }
    __syncthreads();

    // ---- stage 1: h[16][256] = sA @ W1t + b1 ----
    size_t brow[4];
#pragma unroll
    for (int j = 0; j < 4; ++j) brow[j] = (size_t)(wn + j * 16 + fm) * 512 + fk;

    f16x8 wp[4][4];
#pragma unroll
    for (int s = 0; s < 4; ++s)
#pragma unroll
        for (int j = 0; j < 4; ++j)
            wp[s][j] = *(const f16x8*)&W1t[brow[j] + s * 32];

    f32x4 acc[4] = {};
    f16x8 a_cur = *(const f16x8*)&sA[fm * APAD + fk];
#pragma unroll
    for (int kb = 0; kb < 512; kb += 32) {
        int slot = (kb >> 5) & 3;
        f16x8 a_nxt;
        if (kb + 32 < 512) a_nxt = *(const f16x8*)&sA[fm * APAD + kb + 32 + fk];
        f16x8 w0 = wp[slot][0], w1 = wp[slot][1], w2 = wp[slot][2], w3 = wp[slot][3];
        if (kb + 128 < 512) {
#pragma unroll
            for (int j = 0; j < 4; ++j)
                wp[slot][j] = *(const f16x8*)&W1t[brow[j] + kb + 128];
        }
        acc[0] = __builtin_amdgcn_mfma_f32_16x16x32_f16(a_cur, w0, acc[0], 0, 0, 0);
        acc[1] = __builtin_amdgcn_mfma_f32_16x16x32_f16(a_cur, w1, acc[1], 0, 0, 0);
        acc[2] = __builtin_amdgcn_mfma_f32_16x16x32_f16(a_cur, w2, acc[2], 0, 0, 0);
        acc[3] = __builtin_amdgcn_mfma_f32_16x16x32_f16(a_cur, w3, acc[3], 0, 0, 0);
        if (kb + 32 < 512) a_cur = a_nxt;
    }

    // epilogue 1: hbuf[row][ncol], row = q*4+r, ncol = wn + j*16 + fm
#pragma unroll
    for (int j = 0; j < 4; ++j) {
        int ncol = wn + j * 16 + fm;
        float bv = b1[ncol];
#pragma unroll
        for (int r = 0; r < 4; ++r)
            hbuf[(q * 4 + r) * HPAD + ncol] = (_Float16)(acc[j][r] + bv);
    }
    __syncthreads();

    // ---- stage 2: out[16][256] = tanh(h @ W2t + b2) ----
    size_t brow2[4];
#pragma unroll
    for (int j = 0; j < 4; ++j) brow2[j] = (size_t)(wn + j * 16 + fm) * 256 + fk;

#pragma unroll
    for (int s = 0; s < 4; ++s)
#pragma unroll
        for (int j = 0; j < 4; ++j)
            wp[s][j] = *(const f16x8*)&W2t[brow2[j] + s * 32];

    f32x4 acc2[4] = {};
    a_cur = *(const f16x8*)&hbuf[fm * HPAD + fk];
#pragma unroll
    for (int kb = 0; kb < 256; kb += 32) {
        int slot = (kb >> 5) & 3;
        f16x8 a_nxt;
        if (kb + 32 < 256) a_nxt = *(const f16x8*)&hbuf[fm * HPAD + kb + 32 + fk];
        f16x8 w0 = wp[slot][0], w1 = wp[slot][1], w2 = wp[slot][2], w3 = wp[slot][3];
        if (kb + 128 < 256) {
#pragma unroll
            for (int j = 0; j < 4; ++j)
                wp[slot][j] = *(const f16x8*)&W2t[brow2[j] + kb + 128];
        }
        acc2[0] = __builtin_amdgcn_mfma_f32_16x16x32_f16(a_cur, w0, acc2[0], 0, 0, 0);
        acc2[1] = __builtin_amdgcn_mfma_f32_16x16x32_f16(a_cur, w1, acc2[1], 0, 0, 0);
        acc2[2] = __builtin_amdgcn_mfma_f32_16x16x32_f16(a_cur, w2, acc2[2], 0, 0, 0);
        acc2[3] = __builtin_amdgcn_mfma_f32_16x16x32_f16(a_cur, w3, acc2[3], 0, 0, 0);
        if (kb + 32 < 256) a_cur = a_nxt;
    }

    // epilogue 2
#pragma unroll
    for (int j = 0; j < 4; ++j) {
        int ncol = wn + j * 16 + fm;
        float bv = b2[ncol];
#pragma unroll
        for (int r = 0; r < 4; ++r) {
            int row = m0 + q * 4 + r;
            if (row < M) out[(size_t)row * 256 + ncol] = tanhf(acc2[j][r] + bv);
        }
    }
}

// ---------------------------------------------------------------------------
extern "C" void kernel_launch(void* const* d_in, const int* in_sizes, int n_in,
                              void* d_out, int out_size, void* d_ws, size_t ws_size,
                              hipStream_t stream) {
    const float* nf  = (const float*)d_in[0];   // [N, 256] fp32
    const float* W1  = (const float*)d_in[1];   // [512, 256]
    const float* b1  = (const float*)d_in[2];   // [256]
    const float* W2  = (const float*)d_in[3];   // [256, 256]
    const float* b2  = (const float*)d_in[4];   // [256]
    const int* esrc  = (const int*)d_in[5];     // [E]
    const int* edst  = (const int*)d_in[6];     // [E]
    float* out = (float*)d_out;                 // [N, 256] fp32

    int N = in_sizes[0] / H2;
    int E = in_sizes[5];

    char* ws = (char*)d_ws;
    size_t off = 0;
    auto take = [&](size_t bytes) { size_t o = off; off += (bytes + 255) / 256 * 256; return o; };
    int*       cursor = (int*)(ws + take((size_t)N * 4));
    int*       bucket = (int*)(ws + take((size_t)N * MAXDEG * 4));
    _Float16*  cat    = (_Float16*)(ws + take((size_t)N * 256 * 2));
    _Float16*  W1t    = (_Float16*)(ws + take(512 * 256 * 2));
    _Float16*  W2t    = (_Float16*)(ws + take(256 * 256 * 2));

    hipMemsetAsync(cursor, 0, (size_t)N * 4, stream);

    int gE = (E + 255) / 256;                 // 1250 covers edges
    int gR = (N + 7) / 8;                     // 1250 covers cat rows
    int g1 = gE > gR ? gE : gR; if (g1 < 48) g1 = 48;
    prep_scatter<<<g1, 256, 0, stream>>>(nf, W1, W2, esrc, edst, cursor,
                                         bucket, cat, W1t, W2t, N, E);
    gemm12agg<<<(N + 15) / 16, 256, 0, stream>>>(nf, cat, cursor, bucket,
                                                 W1t, W2t, b1, b2, out, N);
}

// Round 13
// 157.708 us; speedup vs baseline: 1.0068x; 1.0068x over previous
//
#include <hip/hip_runtime.h>
#include <math.h>

#define H2 256
#define MAXDEG 128
#define APAD 520   // sA row stride (halves): 1040B rows -> 2-way banks (free)
#define HPAD 264   // hbuf row stride (halves): 528B rows -> 2-way banks (free)

typedef _Float16 f16x8 __attribute__((ext_vector_type(8)));
typedef _Float16 f16x4 __attribute__((ext_vector_type(4)));
typedef float f32x4 __attribute__((ext_vector_type(4)));

// ---------------------------------------------------------------------------
// K1: prep + scatter (cursor pre-zeroed by hipMemsetAsync).
__global__ __launch_bounds__(256) void prep_scatter(
        const float* __restrict__ nf, const float* __restrict__ W1,
        const float* __restrict__ W2, const int* __restrict__ esrc,
        const int* __restrict__ edst, int* __restrict__ cursor,
        int* __restrict__ bucket, _Float16* __restrict__ cat,
        _Float16* __restrict__ W1t, _Float16* __restrict__ W2t,
        int n, int E) {
    __shared__ _Float16 tile[64 * 66];
    int tid = threadIdx.x;
    int blk = blockIdx.x;

    // --- W transpose tiles (blocks 0..47), LDS-tiled, both sides coalesced ---
    if (blk < 48) {
        const float* Wsrc;
        _Float16* Wdst;
        int k0, n0, ldK;
        if (blk < 32) {            // W1 512(k) x 256(n) -> W1t [256][512]
            int kt = blk >> 2, nt = blk & 3;
            k0 = kt * 64; n0 = nt * 64; ldK = 512;
            Wsrc = W1; Wdst = W1t;
        } else {                   // W2 256 x 256 -> W2t [256][256]
            int t2 = blk - 32;
            int kt = t2 >> 2, nt = t2 & 3;
            k0 = kt * 64; n0 = nt * 64; ldK = 256;
            Wsrc = W2; Wdst = W2t;
        }
        for (int idx = tid; idx < 64 * 64; idx += 256) {
            int r = idx >> 6, c = idx & 63;
            tile[r * 66 + c] = (_Float16)Wsrc[(size_t)(k0 + r) * 256 + n0 + c];
        }
        __syncthreads();
        for (int idx = tid; idx < 64 * 64; idx += 256) {
            int cc = idx >> 6, rr = idx & 63;
            Wdst[(size_t)(n0 + cc) * ldK + k0 + rr] = tile[rr * 66 + cc];
        }
    }

    // --- cat convert: 8 rows per block, 2 per wave ---
    int wid  = tid >> 6;
    int lane = tid & 63;
#pragma unroll
    for (int t = 0; t < 2; ++t) {
        int row = blk * 8 + wid * 2 + t;
        if (row < n) {
            float4 v = ((const float4*)nf)[(size_t)row * 64 + lane];
            f16x4 h;
            h.x = (_Float16)v.x; h.y = (_Float16)v.y;
            h.z = (_Float16)v.z; h.w = (_Float16)v.w;
            *(f16x4*)&cat[(size_t)row * 256 + lane * 4] = h;
        }
    }

    // --- edge scatter ---
    int flat = blk * 256 + tid;
    if (flat < E) {
        int d = edst[flat];
        int s = esrc[flat];
        int r = atomicAdd(&cursor[d], 1);
        if (r < MAXDEG) bucket[d * MAXDEG + r] = s;
    }
}

// ---------------------------------------------------------------------------
// K2: fused gather + 2 GEMMs + tanh. Identical to R12 EXCEPT: explicit
// load-batch / sched_barrier(0) / consume-batch structure so the scheduler
// cannot sink loads to their consumers (R5/R9/R12 all compiled to VGPR<=48,
// fully serializing memory latency).
__global__ __launch_bounds__(256, 2) void gemm12agg(
        const float* __restrict__ nf, const _Float16* __restrict__ cat,
        const int* __restrict__ cursor, const int* __restrict__ bucket,
        const _Float16* __restrict__ W1t, const _Float16* __restrict__ W2t,
        const float* __restrict__ b1, const float* __restrict__ b2,
        float* __restrict__ out, int M) {
    __shared__ _Float16 sA[16 * APAD];     // 16.3 KB
    __shared__ _Float16 hbuf[16 * HPAD];   //  8.3 KB

    int tid = threadIdx.x, lane = tid & 63, wid = tid >> 6;   // wid 0..3
    int m0 = blockIdx.x * 16;
    int wn = wid * 64;
    int fm = lane & 15;
    int q  = lane >> 4;
    int fk = q * 8;

    // ---- phase 0a: stage cat -> sA cols [0,256)
    for (int idx = tid; idx < 16 * 32; idx += 256) {
        int row = idx >> 5, g = (idx & 31) * 8;
        int r = m0 + row; if (r >= M) r = M - 1;
        *(uint4*)&sA[row * APAD + g] = *(const uint4*)&cat[(size_t)r * 256 + g];
    }

    // ---- phase 0b: gather pooled for rows 4*wid .. 4*wid+3
    int half = lane >> 5;          // 0: even edge of pair, 1: odd edge
    int c8   = (lane & 31) * 8;    // col base (halves), 16B/lane
#pragma unroll
    for (int t = 0; t < 4; ++t) {
        int rw = wid * 4 + t;
        int node = m0 + rw; if (node >= M) node = M - 1;
        int deg  = cursor[node];
        int degc = deg < MAXDEG ? deg : MAXDEG;
        const int* bk = bucket + (size_t)node * MAXDEG;
        float acc[8] = {0.f, 0.f, 0.f, 0.f, 0.f, 0.f, 0.f, 0.f};
        int e = 0;
        // MLP-8 batches: issue 8 paired loads, fence, then consume
        for (; e + 16 <= degc; e += 16) {
            f16x8 v[8];
#pragma unroll
            for (int p = 0; p < 8; ++p) {
                int s = bk[e + 2 * p + half];
                v[p] = *(const f16x8*)&cat[(size_t)s * 256 + c8];
            }
            __builtin_amdgcn_sched_barrier(0);
#pragma unroll
            for (int p = 0; p < 8; ++p)
#pragma unroll
                for (int k = 0; k < 8; ++k) acc[k] += (float)v[p][k];
        }
        for (; e + 2 <= degc; e += 2) {
            int s = bk[e + half];
            f16x8 v = *(const f16x8*)&cat[(size_t)s * 256 + c8];
#pragma unroll
            for (int k = 0; k < 8; ++k) acc[k] += (float)v[k];
        }
        if (e < degc && half == 0) {
            int s = bk[e];
            f16x8 v = *(const f16x8*)&cat[(size_t)s * 256 + c8];
#pragma unroll
            for (int k = 0; k < 8; ++k) acc[k] += (float)v[k];
        }
        float tot[8];
#pragma unroll
        for (int k = 0; k < 8; ++k) tot[k] = acc[k] + __shfl_down(acc[k], 32);
        if (lane < 32) {
            float4 s0 = ((const float4*)nf)[(size_t)node * 64 + lane * 2];
            float4 s1 = ((const float4*)nf)[(size_t)node * 64 + lane * 2 + 1];
            float fd = (float)deg;
            f16x8 o;
            o[0] = (_Float16)(fd * s0.x - tot[0]);
            o[1] = (_Float16)(fd * s0.y - tot[1]);
            o[2] = (_Float16)(fd * s0.z - tot[2]);
            o[3] = (_Float16)(fd * s0.w - tot[3]);
            o[4] = (_Float16)(fd * s1.x - tot[4]);
            o[5] = (_Float16)(fd * s1.y - tot[5]);
            o[6] = (_Float16)(fd * s1.z - tot[6]);
            o[7] = (_Float16)(fd * s1.w - tot[7]);
            *(f16x8*)&sA[rw * APAD + 256 + lane * 8] = o;
        }
    }
    __syncthreads();

    // ---- stage 1: h[16][256] = sA @ W1t + b1 ----
    size_t brow[4];
#pragma unroll
    for (int j = 0; j < 4; ++j) brow[j] = (size_t)(wn + j * 16 + fm) * 512 + fk;

    f32x4 acc[4] = {};
#pragma unroll
    for (int kc = 0; kc < 512; kc += 128) {
        f16x8 w[4][4], a[4];
#pragma unroll
        for (int s = 0; s < 4; ++s) {
            a[s] = *(const f16x8*)&sA[fm * APAD + kc + s * 32 + fk];
#pragma unroll
            for (int j = 0; j < 4; ++j)
                w[s][j] = *(const f16x8*)&W1t[brow[j] + kc + s * 32];
        }
        __builtin_amdgcn_sched_barrier(0);
#pragma unroll
        for (int s = 0; s < 4; ++s)
#pragma unroll
            for (int j = 0; j < 4; ++j)
                acc[j] = __builtin_amdgcn_mfma_f32_16x16x32_f16(a[s], w[s][j], acc[j], 0, 0, 0);
    }

    // epilogue 1
#pragma unroll
    for (int j = 0; j < 4; ++j) {
        int ncol = wn + j * 16 + fm;
        float bv = b1[ncol];
#pragma unroll
        for (int r = 0; r < 4; ++r)
            hbuf[(q * 4 + r) * HPAD + ncol] = (_Float16)(acc[j][r] + bv);
    }
    __syncthreads();

    // ---- stage 2: out[16][256] = tanh(h @ W2t + b2) ----
    size_t brow2[4];
#pragma unroll
    for (int j = 0; j < 4; ++j) brow2[j] = (size_t)(wn + j * 16 + fm) * 256 + fk;

    f32x4 acc2[4] = {};
#pragma unroll
    for (int kc = 0; kc < 256; kc += 128) {
        f16x8 w[4][4], a[4];
#pragma unroll
        for (int s = 0; s < 4; ++s) {
            a[s] = *(const f16x8*)&hbuf[fm * HPAD + kc + s * 32 + fk];
#pragma unroll
            for (int j = 0; j < 4; ++j)
                w[s][j] = *(const f16x8*)&W2t[brow2[j] + kc + s * 32];
        }
        __builtin_amdgcn_sched_barrier(0);
#pragma unroll
        for (int s = 0; s < 4; ++s)
#pragma unroll
            for (int j = 0; j < 4; ++j)
                acc2[j] = __builtin_amdgcn_mfma_f32_16x16x32_f16(a[s], w[s][j], acc2[j], 0, 0, 0);
    }

    // epilogue 2
#pragma unroll
    for (int j = 0; j < 4; ++j) {
        int ncol = wn + j * 16 + fm;
        float bv = b2[ncol];
#pragma unroll
        for (int r = 0; r < 4; ++r) {
            int row = m0 + q * 4 + r;
            if (row < M) out[(size_t)row * 256 + ncol] = tanhf(acc2[j][r] + bv);
        }
    }
}

// ---------------------------------------------------------------------------
extern "C" void kernel_launch(void* const* d_in, const int* in_sizes, int n_in,
                              void* d_out, int out_size, void* d_ws, size_t ws_size,
                              hipStream_t stream) {
    const float* nf  = (const float*)d_in[0];   // [N, 256] fp32
    const float* W1  = (const float*)d_in[1];   // [512, 256]
    const float* b1  = (const float*)d_in[2];   // [256]
    const float* W2  = (const float*)d_in[3];   // [256, 256]
    const float* b2  = (const float*)d_in[4];   // [256]
    const int* esrc  = (const int*)d_in[5];     // [E]
    const int* edst  = (const int*)d_in[6];     // [E]
    float* out = (float*)d_out;                 // [N, 256] fp32

    int N = in_sizes[0] / H2;
    int E = in_sizes[5];

    char* ws = (char*)d_ws;
    size_t off = 0;
    auto take = [&](size_t bytes) { size_t o = off; off += (bytes + 255) / 256 * 256; return o; };
    int*       cursor = (int*)(ws + take((size_t)N * 4));
    int*       bucket = (int*)(ws + take((size_t)N * MAXDEG * 4));
    _Float16*  cat    = (_Float16*)(ws + take((size_t)N * 256 * 2));
    _Float16*  W1t    = (_Float16*)(ws + take(512 * 256 * 2));
    _Float16*  W2t    = (_Float16*)(ws + take(256 * 256 * 2));

    hipMemsetAsync(cursor, 0, (size_t)N * 4, stream);

    int gE = (E + 255) / 256;
    int gR = (N + 7) / 8;
    int g1 = gE > gR ? gE : gR; if (g1 < 48) g1 = 48;
    prep_scatter<<<g1, 256, 0, stream>>>(nf, W1, W2, esrc, edst, cursor,
                                         bucket, cat, W1t, W2t, N, E);
    gemm12agg<<<(N + 15) / 16, 256, 0, stream>>>(nf, cat, cursor, bucket,
                                                 W1t, W2t, b1, b2, out, N);
}

// Round 14
// 154.152 us; speedup vs baseline: 1.0301x; 1.0231x over previous
//
#include <hip/hip_runtime.h>
#include <math.h>

#define H2 256
#define MAXDEG 128
#define APAD 520   // sA row stride (halves): 1040B rows -> 2-way banks (free)
#define HPAD 264   // hbuf row stride (halves): 528B rows -> 2-way banks (free)

typedef _Float16 f16x8 __attribute__((ext_vector_type(8)));
typedef _Float16 f16x4 __attribute__((ext_vector_type(4)));
typedef _Float16 f16x2 __attribute__((ext_vector_type(2)));
typedef float f32x4 __attribute__((ext_vector_type(4)));

// ---------------------------------------------------------------------------
// K1: prep + scatter (cursor pre-zeroed by hipMemsetAsync).
__global__ __launch_bounds__(256) void prep_scatter(
        const float* __restrict__ nf, const float* __restrict__ W1,
        const float* __restrict__ W2, const int* __restrict__ esrc,
        const int* __restrict__ edst, int* __restrict__ cursor,
        int* __restrict__ bucket, _Float16* __restrict__ cat,
        _Float16* __restrict__ W1t, _Float16* __restrict__ W2t,
        int n, int E) {
    __shared__ _Float16 tile[64 * 66];
    int tid = threadIdx.x;
    int blk = blockIdx.x;

    // --- W transpose tiles (blocks 0..47), LDS-tiled, both sides coalesced ---
    if (blk < 48) {
        const float* Wsrc;
        _Float16* Wdst;
        int k0, n0, ldK;
        if (blk < 32) {            // W1 512(k) x 256(n) -> W1t [256][512]
            int kt = blk >> 2, nt = blk & 3;
            k0 = kt * 64; n0 = nt * 64; ldK = 512;
            Wsrc = W1; Wdst = W1t;
        } else {                   // W2 256 x 256 -> W2t [256][256]
            int t2 = blk - 32;
            int kt = t2 >> 2, nt = t2 & 3;
            k0 = kt * 64; n0 = nt * 64; ldK = 256;
            Wsrc = W2; Wdst = W2t;
        }
        for (int idx = tid; idx < 64 * 64; idx += 256) {
            int r = idx >> 6, c = idx & 63;
            tile[r * 66 + c] = (_Float16)Wsrc[(size_t)(k0 + r) * 256 + n0 + c];
        }
        __syncthreads();
        for (int idx = tid; idx < 64 * 64; idx += 256) {
            int cc = idx >> 6, rr = idx & 63;
            Wdst[(size_t)(n0 + cc) * ldK + k0 + rr] = tile[rr * 66 + cc];
        }
    }

    // --- cat convert: 8 rows per block, 2 per wave ---
    int wid  = tid >> 6;
    int lane = tid & 63;
#pragma unroll
    for (int t = 0; t < 2; ++t) {
        int row = blk * 8 + wid * 2 + t;
        if (row < n) {
            float4 v = ((const float4*)nf)[(size_t)row * 64 + lane];
            f16x4 h;
            h.x = (_Float16)v.x; h.y = (_Float16)v.y;
            h.z = (_Float16)v.z; h.w = (_Float16)v.w;
            *(f16x4*)&cat[(size_t)row * 256 + lane * 4] = h;
        }
    }

    // --- edge scatter ---
    int flat = blk * 256 + tid;
    if (flat < E) {
        int d = edst[flat];
        int s = esrc[flat];
        int r = atomicAdd(&cursor[d], 1);
        if (r < MAXDEG) bucket[d * MAXDEG + r] = s;
    }
}

// ---------------------------------------------------------------------------
// K2: agg, max-parallel form. ONE WAVE PER (node, half-row):
// 20000 waves (~5/SIMD). Lane covers one dword (2 fp16 cols) -> a whole
// edge-row read is ONE instruction costing ONE VGPR, so an 8-deep MLP batch
// is only 8 VGPRs (compiler has no pressure reason to serialize it).
// Indices broadcast from LDS. pooled = deg*nf(fp32) - sum fp16 rows.
__global__ __launch_bounds__(256, 4) void agg_kernel(
        const float* __restrict__ nf, const int* __restrict__ cursor,
        const int* __restrict__ bucket, const _Float16* __restrict__ cat,
        _Float16* __restrict__ pooled, int n) {
    __shared__ int sIdx[4][MAXDEG];
    int tid  = threadIdx.x;
    int wid  = tid >> 6;          // wave 0..3
    int lane = tid & 63;
    int node = blockIdx.x * 2 + (wid >> 1);
    int h    = wid & 1;           // half-row: cols [h*128, h*128+128)
    if (node >= n) node = n - 1;  // clamp (dup work, consistent writes)

    int deg  = cursor[node];
    int degc = deg < MAXDEG ? deg : MAXDEG;
    const int* bk = bucket + (size_t)node * MAXDEG;

    // stage indices (each wave its own copy; L1-hit for the sibling wave)
    sIdx[wid][lane]      = bk[lane];
    sIdx[wid][64 + lane] = bk[64 + lane];
    __builtin_amdgcn_s_waitcnt(0);   // lgkm drain before LDS read-back

    const _Float16* colbase = cat + h * 128 + 2 * lane;
    float a0 = 0.f, a1 = 0.f;
    int e = 0;
    for (; e + 8 <= degc; e += 8) {
        f16x2 v[8];
#pragma unroll
        for (int p = 0; p < 8; ++p) {
            int s = sIdx[wid][e + p];
            v[p] = *(const f16x2*)&colbase[(size_t)s * 256];
        }
        __builtin_amdgcn_sched_barrier(0);
#pragma unroll
        for (int p = 0; p < 8; ++p) { a0 += (float)v[p][0]; a1 += (float)v[p][1]; }
    }
    for (; e < degc; ++e) {
        int s = sIdx[wid][e];
        f16x2 v = *(const f16x2*)&colbase[(size_t)s * 256];
        a0 += (float)v[0]; a1 += (float)v[1];
    }

    float2 self = *(const float2*)&nf[(size_t)node * 256 + h * 128 + 2 * lane];
    float fd = (float)deg;
    f16x2 o;
    o[0] = (_Float16)(fd * self.x - a0);
    o[1] = (_Float16)(fd * self.y - a1);
    *(f16x2*)&pooled[(size_t)node * 256 + h * 128 + 2 * lane] = o;
}

// ---------------------------------------------------------------------------
// K3: fused fp16 MFMA GEMM: out = tanh(([cat|pooled]@W1t+b1)@W2t + b2).
// 512 thr / 8 waves; M-tile 16 (grid 625 -> 4.9 waves/SIMD); wave n-tile 32.
// kc=128 chunks: issue all 8 W b128 loads + 4 A ds_reads, sched_barrier,
// then 8 MFMAs (load sinking defeated). h via LDS.
__global__ __launch_bounds__(512, 2) void gemm12(
        const _Float16* __restrict__ cat, const _Float16* __restrict__ pooled,
        const _Float16* __restrict__ W1t, const _Float16* __restrict__ W2t,
        const float* __restrict__ b1, const float* __restrict__ b2,
        float* __restrict__ out, int M) {
    __shared__ _Float16 sA[16 * APAD];     // 16.3 KB
    __shared__ _Float16 hbuf[16 * HPAD];   //  8.3 KB

    int tid = threadIdx.x, lane = tid & 63, wid = tid >> 6;   // wid 0..7
    int m0 = blockIdx.x * 16;
    int wn = wid * 32;
    int fm = lane & 15;
    int q  = lane >> 4;
    int fk = q * 8;

    // stage A: cat -> cols [0,256), pooled -> cols [256,512); 1024 groups
    for (int idx = tid; idx < 16 * 64; idx += 512) {
        int row = idx >> 6, g = (idx & 63) * 8;
        int r = m0 + row; if (r >= M) r = M - 1;
        uint4 val = (g < 256) ? *(const uint4*)&cat[(size_t)r * 256 + g]
                              : *(const uint4*)&pooled[(size_t)r * 256 + (g - 256)];
        *(uint4*)&sA[row * APAD + g] = val;
    }
    __syncthreads();

    // ---- stage 1: h[16][256] = sA @ W1t + b1 ----
    size_t brow[2];
#pragma unroll
    for (int j = 0; j < 2; ++j) brow[j] = (size_t)(wn + j * 16 + fm) * 512 + fk;

    f32x4 acc[2] = {};
#pragma unroll
    for (int kc = 0; kc < 512; kc += 128) {
        f16x8 w[4][2], a[4];
#pragma unroll
        for (int s = 0; s < 4; ++s) {
            a[s] = *(const f16x8*)&sA[fm * APAD + kc + s * 32 + fk];
#pragma unroll
            for (int j = 0; j < 2; ++j)
                w[s][j] = *(const f16x8*)&W1t[brow[j] + kc + s * 32];
        }
        __builtin_amdgcn_sched_barrier(0);
#pragma unroll
        for (int s = 0; s < 4; ++s)
#pragma unroll
            for (int j = 0; j < 2; ++j)
                acc[j] = __builtin_amdgcn_mfma_f32_16x16x32_f16(a[s], w[s][j], acc[j], 0, 0, 0);
    }

    // epilogue 1: hbuf[row][ncol], row = q*4+r, ncol = wn + j*16 + fm
#pragma unroll
    for (int j = 0; j < 2; ++j) {
        int ncol = wn + j * 16 + fm;
        float bv = b1[ncol];
#pragma unroll
        for (int r = 0; r < 4; ++r)
            hbuf[(q * 4 + r) * HPAD + ncol] = (_Float16)(acc[j][r] + bv);
    }
    __syncthreads();

    // ---- stage 2: out[16][256] = tanh(h @ W2t + b2) ----
    size_t brow2[2];
#pragma unroll
    for (int j = 0; j < 2; ++j) brow2[j] = (size_t)(wn + j * 16 + fm) * 256 + fk;

    f32x4 acc2[2] = {};
#pragma unroll
    for (int kc = 0; kc < 256; kc += 128) {
        f16x8 w[4][2], a[4];
#pragma unroll
        for (int s = 0; s < 4; ++s) {
            a[s] = *(const f16x8*)&hbuf[fm * HPAD + kc + s * 32 + fk];
#pragma unroll
            for (int j = 0; j < 2; ++j)
                w[s][j] = *(const f16x8*)&W2t[brow2[j] + kc + s * 32];
        }
        __builtin_amdgcn_sched_barrier(0);
#pragma unroll
        for (int s = 0; s < 4; ++s)
#pragma unroll
            for (int j = 0; j < 2; ++j)
                acc2[j] = __builtin_amdgcn_mfma_f32_16x16x32_f16(a[s], w[s][j], acc2[j], 0, 0, 0);
    }

    // epilogue 2
#pragma unroll
    for (int j = 0; j < 2; ++j) {
        int ncol = wn + j * 16 + fm;
        float bv = b2[ncol];
#pragma unroll
        for (int r = 0; r < 4; ++r) {
            int row = m0 + q * 4 + r;
            if (row < M) out[(size_t)row * 256 + ncol] = tanhf(acc2[j][r] + bv);
        }
    }
}

// ---------------------------------------------------------------------------
extern "C" void kernel_launch(void* const* d_in, const int* in_sizes, int n_in,
                              void* d_out, int out_size, void* d_ws, size_t ws_size,
                              hipStream_t stream) {
    const float* nf  = (const float*)d_in[0];   // [N, 256] fp32
    const float* W1  = (const float*)d_in[1];   // [512, 256]
    const float* b1  = (const float*)d_in[2];   // [256]
    const float* W2  = (const float*)d_in[3];   // [256, 256]
    const float* b2  = (const float*)d_in[4];   // [256]
    const int* esrc  = (const int*)d_in[5];     // [E]
    const int* edst  = (const int*)d_in[6];     // [E]
    float* out = (float*)d_out;                 // [N, 256] fp32

    int N = in_sizes[0] / H2;
    int E = in_sizes[5];

    char* ws = (char*)d_ws;
    size_t off = 0;
    auto take = [&](size_t bytes) { size_t o = off; off += (bytes + 255) / 256 * 256; return o; };
    int*       cursor = (int*)(ws + take((size_t)N * 4));
    int*       bucket = (int*)(ws + take((size_t)N * MAXDEG * 4));
    _Float16*  cat    = (_Float16*)(ws + take((size_t)N * 256 * 2));
    _Float16*  pooled = (_Float16*)(ws + take((size_t)N * 256 * 2));
    _Float16*  W1t    = (_Float16*)(ws + take(512 * 256 * 2));
    _Float16*  W2t    = (_Float16*)(ws + take(256 * 256 * 2));

    hipMemsetAsync(cursor, 0, (size_t)N * 4, stream);

    int gE = (E + 255) / 256;
    int gR = (N + 7) / 8;
    int g1 = gE > gR ? gE : gR; if (g1 < 48) g1 = 48;
    prep_scatter<<<g1, 256, 0, stream>>>(nf, W1, W2, esrc, edst, cursor,
                                         bucket, cat, W1t, W2t, N, E);
    agg_kernel<<<(N + 1) / 2, 256, 0, stream>>>(nf, cursor, bucket, cat, pooled, N);
    gemm12<<<(N + 15) / 16, 512, 0, stream>>>(cat, pooled, W1t, W2t, b1, b2, out, N);
}